// Round 4
// baseline (157.121 us; speedup 1.0000x reference)
//
#include <hip/hip_runtime.h>
#include <stdint.h>

// WatershedFilter on MI355X — v9.
// R8 post-mortem (v8 2-barrier, bench 153.6 = best): prof run was clock-
// throttled 1.30x (all counters scale uniformly; VALUBusy 52.3 = 68/1.30,
// hbm_gbps 287 = 374/1.30, same FETCH/WRITE) -> at matched clocks v8 ==
// v5 sweep minus ~4 us from halved barriers. Bench-total == k_sweep +
// ~79 us harness constant (stage1 + restore/memset dispatches + gaps).
// With correct 2-cyc wave64 VALU issue: source relax math = ~57K cyc/SIMD
// vs 128K measured -> ~2x inst overhead exists (reg juggling of 180-float
// state), but v6/v7 showed shrinking state or per-px instrumentation
// breaks regalloc. So v9 attacks WORK COUNT:
// v9 = v8 + regalloc-gentle per-block early exit:
//  - detection: per-lane 'anyU = upd ? 1 : anyU' (one v_cndmask reusing
//    the relax vcc; +1 VGPR; NO per-px ballot, NO SGPR chain — v7's
//    mistake). One __any + per-wave LDS flag per ITERATION; consensus
//    read after B1. Exit when a full 4-dir pass made zero strict updates
//    in the whole tile (halo included) = tile-local fixed point ->
//    bit-exact by construction. ITERS=12 stays as the safety bound.
//  - hazards: sconv write (end of body, pre-B1_{i+1}) -> read (post-
//    B1_{i+1}) -> next write (post-B2_{i+1}): both orders closed by
//    barriers. Uniform break (shared consensus) -> no barrier divergence.
//  - TRIPWIRE: if WRITE_SIZE >> 16.4 MB the accumulator spilled -> revert.
// Geometry (= v8): 4 waves stacked vertically, wave = 24 rows x 160 cols
// (lanes 4x16, 6x10 px/lane); tile 96x160, core 64x128, halo 16; grid
// 32x16 = 512 blocks = 2/CU; 2 barriers/iter (B1 pre-pass bottom rows for
// DOWN, B2 post-DOWN top rows for UP); RIGHT/LEFT intra-wave via shfl 1.
// Exactness (validated v5/v8, absmax 0): gray via __fmul_rn/__fadd_rn in
// numpy order; normalize __fdiv_rn(__fsub_rn(v,gmin), fl(gmax-gmin));
// cand=(nd+gray)+1.0f left-assoc; strict '<'; out-of-image px get
// g=d=1e9 pinning dist at exactly 1e9 == reference INF fill; labels at
// fixed point in {1,2} -> out = label - 1.0f.

#define HW    2048
#define N2    (HW * HW)
#define INFV  1e9f
#define TILEY 96
#define TILEX 160
#define COREY 64
#define COREX 128
#define HALO  16
#define NBLK  512
#define ITERS 12

// Stage 1: raw gray -> graw, block min/max -> part[block]. 1024 blocks.
__global__ __launch_bounds__(256) void k_stage1(const float* __restrict__ img,
                                                float* __restrict__ graw,
                                                float2* __restrict__ part) {
  const float4* R = (const float4*)img;
  const float4* G = (const float4*)(img + N2);
  const float4* B = (const float4*)(img + 2 * N2);
  float4* O = (float4*)graw;
  float mn = INFV, mx = 0.0f;
  int base = blockIdx.x * 256 + threadIdx.x;
#pragma unroll
  for (int k = 0; k < 4; ++k) {
    int j = base + k * (1024 * 256);  // N2/4 = 1048576 = 4 * 262144 exact
    float4 r = R[j], g = G[j], b = B[j];
    float4 o;
    o.x = __fadd_rn(__fadd_rn(__fmul_rn(0.2989f, r.x), __fmul_rn(0.587f, g.x)),
                    __fmul_rn(0.114f, b.x));
    o.y = __fadd_rn(__fadd_rn(__fmul_rn(0.2989f, r.y), __fmul_rn(0.587f, g.y)),
                    __fmul_rn(0.114f, b.y));
    o.z = __fadd_rn(__fadd_rn(__fmul_rn(0.2989f, r.z), __fmul_rn(0.587f, g.z)),
                    __fmul_rn(0.114f, b.z));
    o.w = __fadd_rn(__fadd_rn(__fmul_rn(0.2989f, r.w), __fmul_rn(0.587f, g.w)),
                    __fmul_rn(0.114f, b.w));
    O[j] = o;
    mn = fminf(mn, fminf(fminf(o.x, o.y), fminf(o.z, o.w)));
    mx = fmaxf(mx, fmaxf(fmaxf(o.x, o.y), fmaxf(o.z, o.w)));
  }
#pragma unroll
  for (int o = 32; o > 0; o >>= 1) {
    mn = fminf(mn, __shfl_xor(mn, o, 64));
    mx = fmaxf(mx, __shfl_xor(mx, o, 64));
  }
  __shared__ float smn[4], smx[4];
  int wid = threadIdx.x >> 6;
  if ((threadIdx.x & 63) == 0) { smn[wid] = mn; smx[wid] = mx; }
  __syncthreads();
  if (threadIdx.x == 0) {
    mn = fminf(fminf(smn[0], smn[1]), fminf(smn[2], smn[3]));
    mx = fmaxf(fmaxf(smx[0], smx[1]), fmaxf(smx[2], smx[3]));
    part[blockIdx.x] = make_float2(mn, mx);
  }
}

__global__ __launch_bounds__(256, 2) void k_sweep(
    const float* __restrict__ graw, const float2* __restrict__ part,
    float* __restrict__ out) {
  // vertical inter-wave edge buffers only (waves span full tile width)
  __shared__ float Ebd[4][160], Ebl[4][160];  // pre-pass bottom rows
  __shared__ float Etd[4][160], Etl[4][160];  // post-DOWN top rows
  __shared__ float sred[8];
  __shared__ int sconv[4];  // per-wave "any strict update last iteration"
  __shared__ uint8_t stagebuf[TILEY * TILEX];  // 15360 B

  const int tid = threadIdx.x;
  const int wid = tid >> 6;   // 0..3, stacked vertically (wid 0 = top)
  const int lane = tid & 63;
  const int ly = lane >> 4;   // 0..3 lane-rows within wave
  const int lx = lane & 15;   // 0..15 lane-cols (full tile width)

  // ---- prologue: reduce 1024 gray min/max partials ----
  {
    float2 a = part[tid], b = part[tid + 256], c = part[tid + 512],
           e = part[tid + 768];
    float mn = fminf(fminf(a.x, b.x), fminf(c.x, e.x));
    float mx = fmaxf(fmaxf(a.y, b.y), fmaxf(c.y, e.y));
#pragma unroll
    for (int o = 32; o > 0; o >>= 1) {
      mn = fminf(mn, __shfl_xor(mn, o, 64));
      mx = fmaxf(mx, __shfl_xor(mx, o, 64));
    }
    if (lane == 0) { sred[wid] = mn; sred[4 + wid] = mx; }
  }
  if (tid < 4) sconv[tid] = 1;  // "not converged" before first iteration
  __syncthreads();
  const float gmin = fminf(fminf(sred[0], sred[1]), fminf(sred[2], sred[3]));
  const float gmax = fmaxf(fmaxf(sred[4], sred[5]), fmaxf(sred[6], sred[7]));
  const float den = __fsub_rn(gmax, gmin);

  const int by = blockIdx.x >> 4, bx = blockIdx.x & 15;  // 32 x 16
  const int ty = wid * 24 + ly * 6;  // tile-local y of lane row 0
  const int tx = lx * 10;            // tile-local x of lane col 0
  const int gy0 = by * COREY - HALO + ty;
  const int gx0 = bx * COREX - HALO + tx;

  float d[60], g[60], l[60];  // idx = r*10 + c, r in [0,6), c in [0,10)

  // ---------------- load + normalize + markers ----------------
  const bool fullx = (gx0 >= 0) && (gx0 + 10 <= HW);
#pragma unroll
  for (int r = 0; r < 6; ++r) {
    int gy = gy0 + r;
    bool rowin = (gy >= 0) && (gy < HW);
    if (rowin && fullx) {
      const float2* p = (const float2*)(graw + (size_t)gy * HW + gx0);  // gx0 even
      float vr[10];
#pragma unroll
      for (int h = 0; h < 5; ++h) {
        float2 v = p[h];
        vr[2 * h] = v.x;
        vr[2 * h + 1] = v.y;
      }
#pragma unroll
      for (int c = 0; c < 10; ++c) {
        float gv = __fdiv_rn(__fsub_rn(vr[c], gmin), den);
        g[r * 10 + c] = gv;
        bool s1 = gv < 0.3f, s2 = gv > 0.7f;
        d[r * 10 + c] = (s1 || s2) ? 0.0f : INFV;
        l[r * 10 + c] = s1 ? 1.0f : (s2 ? 2.0f : 0.0f);
      }
    } else {
#pragma unroll
      for (int c = 0; c < 10; ++c) {
        int gx = gx0 + c;
        if (rowin && gx >= 0 && gx < HW) {
          float gv = __fdiv_rn(__fsub_rn(graw[(size_t)gy * HW + gx], gmin), den);
          g[r * 10 + c] = gv;
          bool s1 = gv < 0.3f, s2 = gv > 0.7f;
          d[r * 10 + c] = (s1 || s2) ? 0.0f : INFV;
          l[r * 10 + c] = s1 ? 1.0f : (s2 ? 2.0f : 0.0f);
        } else {
          g[r * 10 + c] = INFV;
          d[r * 10 + c] = INFV;
          l[r * 10 + c] = 0.0f;
        }
      }
    }
  }

  // ---------------- iterate (Jacobi per direction, directions sequential) ---
#pragma unroll 1
  for (int it = 0; it < ITERS; ++it) {
    // publish pre-sweep bottom px-row of this wave (for DOWN of wave below)
    if (ly == 3) {
#pragma unroll
      for (int c = 0; c < 10; ++c) {
        Ebd[wid][lx * 10 + c] = d[50 + c];
        Ebl[wid][lx * 10 + c] = l[50 + c];
      }
    }
    __syncthreads();  // B1 (also publishes sconv from previous iteration)

    // early exit: previous full 4-dir pass made zero strict updates in the
    // whole tile -> fixed point; all later iterations are identities.
    if ((sconv[0] | sconv[1] | sconv[2] | sconv[3]) == 0) break;
    int anyU = 0;  // per-lane update accumulator (register, no SGPR chain)

    // ---- DOWN (candidate from row above, pre-pass values) ----
    {
      float pd[10], pl[10];
#pragma unroll
      for (int c = 0; c < 10; ++c) {
        pd[c] = __shfl_up(d[50 + c], 16, 64);
        pl[c] = __shfl_up(l[50 + c], 16, 64);
      }
      if (ly == 0) {
        if (wid == 0) {
#pragma unroll
          for (int c = 0; c < 10; ++c) { pd[c] = INFV; pl[c] = 0.0f; }
        } else {
#pragma unroll
          for (int c = 0; c < 10; ++c) {
            pd[c] = Ebd[wid - 1][lx * 10 + c];
            pl[c] = Ebl[wid - 1][lx * 10 + c];
          }
        }
      }
      // rows 5..1 in place: row r-1 still pre-pass
#pragma unroll
      for (int r = 5; r >= 1; --r) {
#pragma unroll
        for (int c = 0; c < 10; ++c) {
          float cur = d[r * 10 + c];
          float cand = (d[(r - 1) * 10 + c] + g[r * 10 + c]) + 1.0f;
          bool upd = cand < cur;
          d[r * 10 + c] = upd ? cand : cur;
          l[r * 10 + c] = upd ? l[(r - 1) * 10 + c] : l[r * 10 + c];
          anyU = upd ? 1 : anyU;
        }
      }
#pragma unroll
      for (int c = 0; c < 10; ++c) {
        float cur = d[c];
        float cand = (pd[c] + g[c]) + 1.0f;
        bool upd = cand < cur;
        d[c] = upd ? cand : cur;
        l[c] = upd ? pl[c] : l[c];
        anyU = upd ? 1 : anyU;
      }
      if (ly == 0) {  // post-DOWN top row (for UP of wave above)
#pragma unroll
        for (int c = 0; c < 10; ++c) {
          Etd[wid][lx * 10 + c] = d[c];
          Etl[wid][lx * 10 + c] = l[c];
        }
      }
    }
    __syncthreads();  // B2

    // ---- UP (candidate from row below, post-DOWN values) ----
    {
      float pd[10], pl[10];
#pragma unroll
      for (int c = 0; c < 10; ++c) {
        pd[c] = __shfl_down(d[c], 16, 64);
        pl[c] = __shfl_down(l[c], 16, 64);
      }
      if (ly == 3) {
        if (wid == 3) {
#pragma unroll
          for (int c = 0; c < 10; ++c) { pd[c] = INFV; pl[c] = 0.0f; }
        } else {
#pragma unroll
          for (int c = 0; c < 10; ++c) {
            pd[c] = Etd[wid + 1][lx * 10 + c];
            pl[c] = Etl[wid + 1][lx * 10 + c];
          }
        }
      }
#pragma unroll
      for (int r = 0; r <= 4; ++r) {
#pragma unroll
        for (int c = 0; c < 10; ++c) {
          float cur = d[r * 10 + c];
          float cand = (d[(r + 1) * 10 + c] + g[r * 10 + c]) + 1.0f;
          bool upd = cand < cur;
          d[r * 10 + c] = upd ? cand : cur;
          l[r * 10 + c] = upd ? l[(r + 1) * 10 + c] : l[r * 10 + c];
          anyU = upd ? 1 : anyU;
        }
      }
#pragma unroll
      for (int c = 0; c < 10; ++c) {
        float cur = d[50 + c];
        float cand = (pd[c] + g[50 + c]) + 1.0f;
        bool upd = cand < cur;
        d[50 + c] = upd ? cand : cur;
        l[50 + c] = upd ? pl[c] : l[50 + c];
        anyU = upd ? 1 : anyU;
      }
    }
    // no barrier: RIGHT/LEFT are purely intra-wave (wave spans full width)

    // ---- RIGHT (candidate from col left, post-UP values) ----
    {
      float pc[6], plc[6];
#pragma unroll
      for (int r = 0; r < 6; ++r) {
        pc[r] = __shfl_up(d[r * 10 + 9], 1, 64);
        plc[r] = __shfl_up(l[r * 10 + 9], 1, 64);
      }
      if (lx == 0) {  // tile-left edge (wave spans full width)
#pragma unroll
        for (int r = 0; r < 6; ++r) { pc[r] = INFV; plc[r] = 0.0f; }
      }
#pragma unroll
      for (int c = 9; c >= 1; --c) {
#pragma unroll
        for (int r = 0; r < 6; ++r) {
          float cur = d[r * 10 + c];
          float cand = (d[r * 10 + c - 1] + g[r * 10 + c]) + 1.0f;
          bool upd = cand < cur;
          d[r * 10 + c] = upd ? cand : cur;
          l[r * 10 + c] = upd ? l[r * 10 + c - 1] : l[r * 10 + c];
          anyU = upd ? 1 : anyU;
        }
      }
#pragma unroll
      for (int r = 0; r < 6; ++r) {
        float cur = d[r * 10];
        float cand = (pc[r] + g[r * 10]) + 1.0f;
        bool upd = cand < cur;
        d[r * 10] = upd ? cand : cur;
        l[r * 10] = upd ? plc[r] : l[r * 10];
        anyU = upd ? 1 : anyU;
      }
    }

    // ---- LEFT (candidate from col right, post-RIGHT values) ----
    {
      float pc[6], plc[6];
#pragma unroll
      for (int r = 0; r < 6; ++r) {
        pc[r] = __shfl_down(d[r * 10], 1, 64);
        plc[r] = __shfl_down(l[r * 10], 1, 64);
      }
      if (lx == 15) {  // tile-right edge
#pragma unroll
        for (int r = 0; r < 6; ++r) { pc[r] = INFV; plc[r] = 0.0f; }
      }
#pragma unroll
      for (int c = 0; c <= 8; ++c) {
#pragma unroll
        for (int r = 0; r < 6; ++r) {
          float cur = d[r * 10 + c];
          float cand = (d[r * 10 + c + 1] + g[r * 10 + c]) + 1.0f;
          bool upd = cand < cur;
          d[r * 10 + c] = upd ? cand : cur;
          l[r * 10 + c] = upd ? l[r * 10 + c + 1] : l[r * 10 + c];
          anyU = upd ? 1 : anyU;
        }
      }
#pragma unroll
      for (int r = 0; r < 6; ++r) {
        float cur = d[r * 10 + 9];
        float cand = (pc[r] + g[r * 10 + 9]) + 1.0f;
        bool upd = cand < cur;
        d[r * 10 + 9] = upd ? cand : cur;
        l[r * 10 + 9] = upd ? plc[r] : l[r * 10 + 9];
        anyU = upd ? 1 : anyU;
      }
    }

    // publish this iteration's per-wave convergence flag (one ballot per
    // ITERATION, not per pixel); next B1 makes it visible to all waves.
    if (lane == 0) sconv[wid] = 0;     // cleared only by own wave's lane 0...
    // NOTE: must not race with other waves reading sconv post-B1: the read
    // happened before B2 of THIS iteration for all waves; this write is
    // after B2 -> ordered. Combine via __any:
    {
      int wany = __any(anyU);
      if (lane == 0) sconv[wid] = wany;
    }
    // no trailing barrier: next iteration's B1 covers the Ebd/sconv hazard
  }

  // ---------------- epilogue: stage label bytes, write float out ----------
#pragma unroll
  for (int r = 0; r < 6; ++r) {
#pragma unroll
    for (int c = 0; c < 10; ++c) {
      stagebuf[(ty + r) * TILEX + tx + c] = (uint8_t)l[r * 10 + c];
    }
  }
  __syncthreads();

  // labels at fixed point are in {1,2} (validated R4) -> out = label - 1
  const uint32_t* sb32 = (const uint32_t*)stagebuf;
#pragma unroll
  for (int k = 0; k < 8; ++k) {
    int j = tid + k * 256;  // 0..2047 float4s of the 64x128 core
    int y = j >> 5;         // 32 float4 per core row
    int xq = j & 31;
    uint32_t v = sb32[((HALO + y) * TILEX + HALO) / 4 + xq];
    float4 o;
    o.x = (float)(v & 0xFFu) - 1.0f;
    o.y = (float)((v >> 8) & 0xFFu) - 1.0f;
    o.z = (float)((v >> 16) & 0xFFu) - 1.0f;
    o.w = (float)(v >> 24) - 1.0f;
    *(float4*)(out + (size_t)(by * COREY + y) * HW + bx * COREX + xq * 4) = o;
  }
}

extern "C" void kernel_launch(void* const* d_in, const int* in_sizes, int n_in,
                              void* d_out, int out_size, void* d_ws, size_t ws_size,
                              hipStream_t stream) {
  const float* img = (const float*)d_in[0];
  float* out = (float*)d_out;
  char* ws = (char*)d_ws;

  float2* part = (float2*)ws;            // 8 KB (1024 float2)
  float* graw = (float*)(ws + 16384);    // 16.8 MB

  k_stage1<<<1024, 256, 0, stream>>>(img, graw, part);
  k_sweep<<<NBLK, 256, 0, stream>>>(graw, part, out);
}

// Round 5
// 139.270 us; speedup vs baseline: 1.1282x; 1.1282x over previous
//
#include <hip/hip_runtime.h>
#include <stdint.h>

// WatershedFilter on MI355X — v10.
// R9 post-mortem (v9 = v8 + anyU exit): TRIPWIRE FIRED. WRITE_SIZE
// 16.4->73 MB: even ONE extra live cndmask accumulator spilled to scratch.
// Conclusion: at the 6x10-lane geometry, live state (180 + ~70 temps) sits
// EXACTLY at the 256 reg/wave budget (128 arch + 128 acc). Zero headroom.
// Yet k_sweep was ~75.5 us WITH ~57 MB spill ~= v8's 74.5 without -> the
// early exit genuinely saved ~10-13 us (tiles converge ~iter 10); spill ate
// it. v8 (153.6 bench) best so far.
// v10 = buy headroom + halo efficiency together with a 512-thread block:
//  - 8 waves stacked vertically, wave = 20 rows x 160 cols (lanes 4x16,
//    5x10 px/lane). Tile 160x160, core 128x128, halo 16 (>= ITERS=12,
//    validated margin) -> grid 16x16 = 256 blocks = EXACTLY 1/CU, still
//    2 waves/SIMD (same latency hiding as v8).
//  - work ratio 160^2/128^2 = 1.5625 vs 1.875 -> -17% relax work.
//  - lane state d/g/l[50]=150 + pd/pl[10]+pc/plc[5] + temps ~= 185 << 256
//    -> anyU exit accumulator now fits WITHOUT scratch.
//  - early exit (bit-exact): break only after a full 4-direction pass made
//    zero strict updates in the whole tile (= tile-local fixed point; all
//    later iterations are identities). At 1 block/CU this only trims the
//    slowest tile's identity iterations (~1 iter) — main win is -17% work.
//  - TRIPWIRE: if WRITE_SIZE >> 16.4 MB it spilled -> revert to v8.
// Protocol (= v8): 2 barriers/iter. B1 covers pre-pass bottom rows (Ebd,
// for DOWN) + sconv consensus; B2 covers post-DOWN top rows (Etd, for UP).
// RIGHT/LEFT purely intra-wave (wave spans full tile width; shfl by 1).
// Hazards: Ebd read (B1_i..B2_i) vs write (pre-B1_{i+1}, after B2_i) ok;
// Etd read (post-B2_i) vs write (post-B1_{i+1}) ok; sconv write (post-
// B2_i) -> read (post-B1_{i+1}) -> next write (post-B2_{i+1}) ok. Break
// is uniform (shared consensus) -> no barrier divergence.
// Exactness (validated v5/v8, absmax 0): gray via __fmul_rn/__fadd_rn in
// numpy order; normalize __fdiv_rn(__fsub_rn(v,gmin), fl(gmax-gmin));
// cand=(nd+gray)+1.0f left-assoc; strict '<'; Jacobi-per-direction via
// in-place anti-sweep orders (DOWN r=4..1 then 0; UP r=0..3 then 4;
// RIGHT c=9..1 then 0; LEFT c=0..8 then 9 — every read is pre-pass);
// out-of-image px get g=d=1e9 pinning dist at exactly 1e9 == reference
// INF fill; labels at fixed point in {1,2} -> out = label - 1.0f.

#define HW    2048
#define N2    (HW * HW)
#define INFV  1e9f
#define TILEY 160
#define TILEX 160
#define COREY 128
#define COREX 128
#define HALO  16
#define NBLK  256
#define ITERS 12

// Stage 1: raw gray -> graw, block min/max -> part[block]. 1024 blocks.
__global__ __launch_bounds__(256) void k_stage1(const float* __restrict__ img,
                                                float* __restrict__ graw,
                                                float2* __restrict__ part) {
  const float4* R = (const float4*)img;
  const float4* G = (const float4*)(img + N2);
  const float4* B = (const float4*)(img + 2 * N2);
  float4* O = (float4*)graw;
  float mn = INFV, mx = 0.0f;
  int base = blockIdx.x * 256 + threadIdx.x;
#pragma unroll
  for (int k = 0; k < 4; ++k) {
    int j = base + k * (1024 * 256);  // N2/4 = 1048576 = 4 * 262144 exact
    float4 r = R[j], g = G[j], b = B[j];
    float4 o;
    o.x = __fadd_rn(__fadd_rn(__fmul_rn(0.2989f, r.x), __fmul_rn(0.587f, g.x)),
                    __fmul_rn(0.114f, b.x));
    o.y = __fadd_rn(__fadd_rn(__fmul_rn(0.2989f, r.y), __fmul_rn(0.587f, g.y)),
                    __fmul_rn(0.114f, b.y));
    o.z = __fadd_rn(__fadd_rn(__fmul_rn(0.2989f, r.z), __fmul_rn(0.587f, g.z)),
                    __fmul_rn(0.114f, b.z));
    o.w = __fadd_rn(__fadd_rn(__fmul_rn(0.2989f, r.w), __fmul_rn(0.587f, g.w)),
                    __fmul_rn(0.114f, b.w));
    O[j] = o;
    mn = fminf(mn, fminf(fminf(o.x, o.y), fminf(o.z, o.w)));
    mx = fmaxf(mx, fmaxf(fmaxf(o.x, o.y), fmaxf(o.z, o.w)));
  }
#pragma unroll
  for (int o = 32; o > 0; o >>= 1) {
    mn = fminf(mn, __shfl_xor(mn, o, 64));
    mx = fmaxf(mx, __shfl_xor(mx, o, 64));
  }
  __shared__ float smn[4], smx[4];
  int wid = threadIdx.x >> 6;
  if ((threadIdx.x & 63) == 0) { smn[wid] = mn; smx[wid] = mx; }
  __syncthreads();
  if (threadIdx.x == 0) {
    mn = fminf(fminf(smn[0], smn[1]), fminf(smn[2], smn[3]));
    mx = fmaxf(fmaxf(smx[0], smx[1]), fmaxf(smx[2], smx[3]));
    part[blockIdx.x] = make_float2(mn, mx);
  }
}

__global__ __launch_bounds__(512, 2) void k_sweep(
    const float* __restrict__ graw, const float2* __restrict__ part,
    float* __restrict__ out) {
  // vertical inter-wave edge buffers only (waves span full tile width)
  __shared__ float Ebd[8][160], Ebl[8][160];  // pre-pass bottom rows
  __shared__ float Etd[8][160], Etl[8][160];  // post-DOWN top rows
  __shared__ float sred[16];
  __shared__ int sconv[8];  // per-wave "any strict update last iteration"
  __shared__ uint8_t stagebuf[TILEY * TILEX];  // 25600 B

  const int tid = threadIdx.x;
  const int wid = tid >> 6;   // 0..7, stacked vertically (wid 0 = top)
  const int lane = tid & 63;
  const int ly = lane >> 4;   // 0..3 lane-rows within wave
  const int lx = lane & 15;   // 0..15 lane-cols (full tile width)

  // ---- prologue: reduce 1024 gray min/max partials ----
  {
    float2 a = part[tid], b = part[tid + 512];
    float mn = fminf(a.x, b.x);
    float mx = fmaxf(a.y, b.y);
#pragma unroll
    for (int o = 32; o > 0; o >>= 1) {
      mn = fminf(mn, __shfl_xor(mn, o, 64));
      mx = fmaxf(mx, __shfl_xor(mx, o, 64));
    }
    if (lane == 0) { sred[wid] = mn; sred[8 + wid] = mx; }
  }
  if (tid < 8) sconv[tid] = 1;  // "not converged" before first iteration
  __syncthreads();
  const float gmin =
      fminf(fminf(fminf(sred[0], sred[1]), fminf(sred[2], sred[3])),
            fminf(fminf(sred[4], sred[5]), fminf(sred[6], sred[7])));
  const float gmax =
      fmaxf(fmaxf(fmaxf(sred[8], sred[9]), fmaxf(sred[10], sred[11])),
            fmaxf(fmaxf(sred[12], sred[13]), fmaxf(sred[14], sred[15])));
  const float den = __fsub_rn(gmax, gmin);

  const int by = blockIdx.x >> 4, bx = blockIdx.x & 15;  // 16 x 16
  const int ty = wid * 20 + ly * 5;  // tile-local y of lane row 0
  const int tx = lx * 10;            // tile-local x of lane col 0
  const int gy0 = by * COREY - HALO + ty;
  const int gx0 = bx * COREX - HALO + tx;

  float d[50], g[50], l[50];  // idx = r*10 + c, r in [0,5), c in [0,10)

  // ---------------- load + normalize + markers ----------------
  const bool fullx = (gx0 >= 0) && (gx0 + 10 <= HW);
#pragma unroll
  for (int r = 0; r < 5; ++r) {
    int gy = gy0 + r;
    bool rowin = (gy >= 0) && (gy < HW);
    if (rowin && fullx) {
      const float2* p = (const float2*)(graw + (size_t)gy * HW + gx0);  // gx0 even
      float vr[10];
#pragma unroll
      for (int h = 0; h < 5; ++h) {
        float2 v = p[h];
        vr[2 * h] = v.x;
        vr[2 * h + 1] = v.y;
      }
#pragma unroll
      for (int c = 0; c < 10; ++c) {
        float gv = __fdiv_rn(__fsub_rn(vr[c], gmin), den);
        g[r * 10 + c] = gv;
        bool s1 = gv < 0.3f, s2 = gv > 0.7f;
        d[r * 10 + c] = (s1 || s2) ? 0.0f : INFV;
        l[r * 10 + c] = s1 ? 1.0f : (s2 ? 2.0f : 0.0f);
      }
    } else {
#pragma unroll
      for (int c = 0; c < 10; ++c) {
        int gx = gx0 + c;
        if (rowin && gx >= 0 && gx < HW) {
          float gv = __fdiv_rn(__fsub_rn(graw[(size_t)gy * HW + gx], gmin), den);
          g[r * 10 + c] = gv;
          bool s1 = gv < 0.3f, s2 = gv > 0.7f;
          d[r * 10 + c] = (s1 || s2) ? 0.0f : INFV;
          l[r * 10 + c] = s1 ? 1.0f : (s2 ? 2.0f : 0.0f);
        } else {
          g[r * 10 + c] = INFV;
          d[r * 10 + c] = INFV;
          l[r * 10 + c] = 0.0f;
        }
      }
    }
  }

  // ---------------- iterate (Jacobi per direction, directions sequential) ---
#pragma unroll 1
  for (int it = 0; it < ITERS; ++it) {
    // publish pre-sweep bottom px-row of this wave (for DOWN of wave below)
    if (ly == 3) {
#pragma unroll
      for (int c = 0; c < 10; ++c) {
        Ebd[wid][lx * 10 + c] = d[40 + c];
        Ebl[wid][lx * 10 + c] = l[40 + c];
      }
    }
    __syncthreads();  // B1 (also publishes sconv from previous iteration)

    // early exit: previous full 4-dir pass made zero strict updates in the
    // whole tile -> fixed point; all later iterations are identities.
    if ((sconv[0] | sconv[1] | sconv[2] | sconv[3] | sconv[4] | sconv[5] |
         sconv[6] | sconv[7]) == 0)
      break;
    int anyU = 0;  // per-lane update accumulator (register)

    // ---- DOWN (candidate from row above, pre-pass values) ----
    {
      float pd[10], pl[10];
#pragma unroll
      for (int c = 0; c < 10; ++c) {
        pd[c] = __shfl_up(d[40 + c], 16, 64);
        pl[c] = __shfl_up(l[40 + c], 16, 64);
      }
      if (ly == 0) {
        if (wid == 0) {
#pragma unroll
          for (int c = 0; c < 10; ++c) { pd[c] = INFV; pl[c] = 0.0f; }
        } else {
#pragma unroll
          for (int c = 0; c < 10; ++c) {
            pd[c] = Ebd[wid - 1][lx * 10 + c];
            pl[c] = Ebl[wid - 1][lx * 10 + c];
          }
        }
      }
      // rows 4..1 in place: row r-1 still pre-pass
#pragma unroll
      for (int r = 4; r >= 1; --r) {
#pragma unroll
        for (int c = 0; c < 10; ++c) {
          float cur = d[r * 10 + c];
          float cand = (d[(r - 1) * 10 + c] + g[r * 10 + c]) + 1.0f;
          bool upd = cand < cur;
          d[r * 10 + c] = upd ? cand : cur;
          l[r * 10 + c] = upd ? l[(r - 1) * 10 + c] : l[r * 10 + c];
          anyU = upd ? 1 : anyU;
        }
      }
#pragma unroll
      for (int c = 0; c < 10; ++c) {
        float cur = d[c];
        float cand = (pd[c] + g[c]) + 1.0f;
        bool upd = cand < cur;
        d[c] = upd ? cand : cur;
        l[c] = upd ? pl[c] : l[c];
        anyU = upd ? 1 : anyU;
      }
      if (ly == 0) {  // post-DOWN top row (for UP of wave above)
#pragma unroll
        for (int c = 0; c < 10; ++c) {
          Etd[wid][lx * 10 + c] = d[c];
          Etl[wid][lx * 10 + c] = l[c];
        }
      }
    }
    __syncthreads();  // B2

    // ---- UP (candidate from row below, post-DOWN values) ----
    {
      float pd[10], pl[10];
#pragma unroll
      for (int c = 0; c < 10; ++c) {
        pd[c] = __shfl_down(d[c], 16, 64);
        pl[c] = __shfl_down(l[c], 16, 64);
      }
      if (ly == 3) {
        if (wid == 7) {
#pragma unroll
          for (int c = 0; c < 10; ++c) { pd[c] = INFV; pl[c] = 0.0f; }
        } else {
#pragma unroll
          for (int c = 0; c < 10; ++c) {
            pd[c] = Etd[wid + 1][lx * 10 + c];
            pl[c] = Etl[wid + 1][lx * 10 + c];
          }
        }
      }
#pragma unroll
      for (int r = 0; r <= 3; ++r) {
#pragma unroll
        for (int c = 0; c < 10; ++c) {
          float cur = d[r * 10 + c];
          float cand = (d[(r + 1) * 10 + c] + g[r * 10 + c]) + 1.0f;
          bool upd = cand < cur;
          d[r * 10 + c] = upd ? cand : cur;
          l[r * 10 + c] = upd ? l[(r + 1) * 10 + c] : l[r * 10 + c];
          anyU = upd ? 1 : anyU;
        }
      }
#pragma unroll
      for (int c = 0; c < 10; ++c) {
        float cur = d[40 + c];
        float cand = (pd[c] + g[40 + c]) + 1.0f;
        bool upd = cand < cur;
        d[40 + c] = upd ? cand : cur;
        l[40 + c] = upd ? pl[c] : l[40 + c];
        anyU = upd ? 1 : anyU;
      }
    }
    // no barrier: RIGHT/LEFT are purely intra-wave (wave spans full width)

    // ---- RIGHT (candidate from col left, post-UP values) ----
    {
      float pc[5], plc[5];
#pragma unroll
      for (int r = 0; r < 5; ++r) {
        pc[r] = __shfl_up(d[r * 10 + 9], 1, 64);
        plc[r] = __shfl_up(l[r * 10 + 9], 1, 64);
      }
      if (lx == 0) {  // tile-left edge (wave spans full width)
#pragma unroll
        for (int r = 0; r < 5; ++r) { pc[r] = INFV; plc[r] = 0.0f; }
      }
#pragma unroll
      for (int c = 9; c >= 1; --c) {
#pragma unroll
        for (int r = 0; r < 5; ++r) {
          float cur = d[r * 10 + c];
          float cand = (d[r * 10 + c - 1] + g[r * 10 + c]) + 1.0f;
          bool upd = cand < cur;
          d[r * 10 + c] = upd ? cand : cur;
          l[r * 10 + c] = upd ? l[r * 10 + c - 1] : l[r * 10 + c];
          anyU = upd ? 1 : anyU;
        }
      }
#pragma unroll
      for (int r = 0; r < 5; ++r) {
        float cur = d[r * 10];
        float cand = (pc[r] + g[r * 10]) + 1.0f;
        bool upd = cand < cur;
        d[r * 10] = upd ? cand : cur;
        l[r * 10] = upd ? plc[r] : l[r * 10];
        anyU = upd ? 1 : anyU;
      }
    }

    // ---- LEFT (candidate from col right, post-RIGHT values) ----
    {
      float pc[5], plc[5];
#pragma unroll
      for (int r = 0; r < 5; ++r) {
        pc[r] = __shfl_down(d[r * 10], 1, 64);
        plc[r] = __shfl_down(l[r * 10], 1, 64);
      }
      if (lx == 15) {  // tile-right edge
#pragma unroll
        for (int r = 0; r < 5; ++r) { pc[r] = INFV; plc[r] = 0.0f; }
      }
#pragma unroll
      for (int c = 0; c <= 8; ++c) {
#pragma unroll
        for (int r = 0; r < 5; ++r) {
          float cur = d[r * 10 + c];
          float cand = (d[r * 10 + c + 1] + g[r * 10 + c]) + 1.0f;
          bool upd = cand < cur;
          d[r * 10 + c] = upd ? cand : cur;
          l[r * 10 + c] = upd ? l[r * 10 + c + 1] : l[r * 10 + c];
          anyU = upd ? 1 : anyU;
        }
      }
#pragma unroll
      for (int r = 0; r < 5; ++r) {
        float cur = d[r * 10 + 9];
        float cand = (pc[r] + g[r * 10 + 9]) + 1.0f;
        bool upd = cand < cur;
        d[r * 10 + 9] = upd ? cand : cur;
        l[r * 10 + 9] = upd ? plc[r] : l[r * 10 + 9];
        anyU = upd ? 1 : anyU;
      }
    }

    // publish this iteration's per-wave convergence flag (one __any per
    // ITERATION); next B1 makes it visible to all waves.
    {
      int wany = __any(anyU);
      if (lane == 0) sconv[wid] = wany;
    }
    // no trailing barrier: next iteration's B1 covers the Ebd/sconv hazard
  }

  // ---------------- epilogue: stage label bytes, write float out ----------
#pragma unroll
  for (int r = 0; r < 5; ++r) {
#pragma unroll
    for (int c = 0; c < 10; ++c) {
      stagebuf[(ty + r) * TILEX + tx + c] = (uint8_t)l[r * 10 + c];
    }
  }
  __syncthreads();

  // labels at fixed point are in {1,2} (validated R4) -> out = label - 1
  const uint32_t* sb32 = (const uint32_t*)stagebuf;
#pragma unroll
  for (int k = 0; k < 8; ++k) {
    int j = tid + k * 512;  // 0..4095 float4s of the 128x128 core
    int y = j >> 5;         // 32 float4 per core row
    int xq = j & 31;
    uint32_t v = sb32[((HALO + y) * TILEX + HALO) / 4 + xq];
    float4 o;
    o.x = (float)(v & 0xFFu) - 1.0f;
    o.y = (float)((v >> 8) & 0xFFu) - 1.0f;
    o.z = (float)((v >> 16) & 0xFFu) - 1.0f;
    o.w = (float)(v >> 24) - 1.0f;
    *(float4*)(out + (size_t)(by * COREY + y) * HW + bx * COREX + xq * 4) = o;
  }
}

extern "C" void kernel_launch(void* const* d_in, const int* in_sizes, int n_in,
                              void* d_out, int out_size, void* d_ws, size_t ws_size,
                              hipStream_t stream) {
  const float* img = (const float*)d_in[0];
  float* out = (float*)d_out;
  char* ws = (char*)d_ws;

  float2* part = (float2*)ws;            // 8 KB (1024 float2)
  float* graw = (float*)(ws + 16384);    // 16.8 MB

  k_stage1<<<1024, 256, 0, stream>>>(img, graw, part);
  k_sweep<<<NBLK, 512, 0, stream>>>(graw, part, out);
}

// Round 6
// 135.718 us; speedup vs baseline: 1.1577x; 1.0262x over previous
//
#include <hip/hip_runtime.h>
#include <stdint.h>

// WatershedFilter on MI355X — v11.
// R10 post-mortem (v10, k_sweep 55.4 us, bench 139.3 = best): WIN, no
// spill. Remaining stall: VALUBusy only 45% at 1 block/CU — the single
// 8-wave block stalls the whole CU at both barriers and leaves 2 waves/
// SIMD for latency hiding. v8 evidence: same 8 waves/CU as 2 blocks ->
// 68% busy. Barrier cost itself ~4.6 us; dominant stall is intra-phase
// shuffle/LDS dependency chains at 2 waves/SIMD.
// v11 = SAME tile/work (160x160 tile, 128x128 core, 256 blocks = 1/CU,
// ratio 1.5625) but 1024-thread blocks -> 4 waves/SIMD:
//  - 16 waves stacked vertically, wave = 10 rows x 160 cols, lanes 2x32,
//    lane = 5x5 px. State d/g/l[25]=75 + temps ~= 115 -> fits ~arch
//    VGPRs (less AGPR traffic); shuffle count/lane halves.
//  - work per CU IDENTICAL to v10 -> bounded downside: if barrier skew
//    (16-wave sync) eats the TLP gain, time stays ~55 us; no work
//    regression possible.
//  - TRIPWIRE: WRITE_SIZE >> 16.4 MB = spill -> revert to v10.
// Protocol (= v10): 2 barriers/iter. B1: pre-pass bottom rows (Ebd, for
// DOWN) + sconv consensus; B2: post-DOWN top rows (Etd, for UP).
// RIGHT/LEFT purely intra-wave (wave spans full width; shfl by 1, lx
// edge-masked; the lane32<-lane31 shfl wrap is masked by lx==0/31).
// Early exit (bit-exact): break only after a full 4-dir pass with zero
// strict updates anywhere in the tile (all later iters are identities).
// Exactness (validated v5/v8/v10, absmax 0): gray via __fmul_rn/
// __fadd_rn in numpy order; normalize __fdiv_rn(__fsub_rn(v,gmin),
// fl(gmax-gmin)); cand=(nd+gray)+1.0f left-assoc; strict '<'; Jacobi
// anti-sweep in-place orders (DOWN r=4..1 then 0; UP r=0..3 then 4;
// RIGHT c=4..1 then 0; LEFT c=0..3 then 4 — every read pre-pass);
// out-of-image px get g=d=1e9 pinning dist at exactly 1e9 == reference
// INF fill; labels at fixed point in {1,2} -> out = label - 1.0f.

#define HW    2048
#define N2    (HW * HW)
#define INFV  1e9f
#define TILEY 160
#define TILEX 160
#define COREY 128
#define COREX 128
#define HALO  16
#define NBLK  256
#define ITERS 12

// Stage 1: raw gray -> graw, block min/max -> part[block]. 1024 blocks.
__global__ __launch_bounds__(256) void k_stage1(const float* __restrict__ img,
                                                float* __restrict__ graw,
                                                float2* __restrict__ part) {
  const float4* R = (const float4*)img;
  const float4* G = (const float4*)(img + N2);
  const float4* B = (const float4*)(img + 2 * N2);
  float4* O = (float4*)graw;
  float mn = INFV, mx = 0.0f;
  int base = blockIdx.x * 256 + threadIdx.x;
#pragma unroll
  for (int k = 0; k < 4; ++k) {
    int j = base + k * (1024 * 256);  // N2/4 = 1048576 = 4 * 262144 exact
    float4 r = R[j], g = G[j], b = B[j];
    float4 o;
    o.x = __fadd_rn(__fadd_rn(__fmul_rn(0.2989f, r.x), __fmul_rn(0.587f, g.x)),
                    __fmul_rn(0.114f, b.x));
    o.y = __fadd_rn(__fadd_rn(__fmul_rn(0.2989f, r.y), __fmul_rn(0.587f, g.y)),
                    __fmul_rn(0.114f, b.y));
    o.z = __fadd_rn(__fadd_rn(__fmul_rn(0.2989f, r.z), __fmul_rn(0.587f, g.z)),
                    __fmul_rn(0.114f, b.z));
    o.w = __fadd_rn(__fadd_rn(__fmul_rn(0.2989f, r.w), __fmul_rn(0.587f, g.w)),
                    __fmul_rn(0.114f, b.w));
    O[j] = o;
    mn = fminf(mn, fminf(fminf(o.x, o.y), fminf(o.z, o.w)));
    mx = fmaxf(mx, fmaxf(fmaxf(o.x, o.y), fmaxf(o.z, o.w)));
  }
#pragma unroll
  for (int o = 32; o > 0; o >>= 1) {
    mn = fminf(mn, __shfl_xor(mn, o, 64));
    mx = fmaxf(mx, __shfl_xor(mx, o, 64));
  }
  __shared__ float smn[4], smx[4];
  int wid = threadIdx.x >> 6;
  if ((threadIdx.x & 63) == 0) { smn[wid] = mn; smx[wid] = mx; }
  __syncthreads();
  if (threadIdx.x == 0) {
    mn = fminf(fminf(smn[0], smn[1]), fminf(smn[2], smn[3]));
    mx = fmaxf(fmaxf(smx[0], smx[1]), fmaxf(smx[2], smx[3]));
    part[blockIdx.x] = make_float2(mn, mx);
  }
}

__global__ __launch_bounds__(1024, 2) void k_sweep(
    const float* __restrict__ graw, const float2* __restrict__ part,
    float* __restrict__ out) {
  // vertical inter-wave edge buffers only (waves span full tile width)
  __shared__ float Ebd[16][160], Ebl[16][160];  // pre-pass bottom rows
  __shared__ float Etd[16][160], Etl[16][160];  // post-DOWN top rows
  __shared__ float sred[32];
  __shared__ int sconv[16];  // per-wave "any strict update last iteration"
  __shared__ uint8_t stagebuf[TILEY * TILEX];  // 25600 B

  const int tid = threadIdx.x;
  const int wid = tid >> 6;   // 0..15, stacked vertically (wid 0 = top)
  const int lane = tid & 63;
  const int ly = lane >> 5;   // 0..1 lane-rows within wave
  const int lx = lane & 31;   // 0..31 lane-cols (full tile width)

  // ---- prologue: reduce 1024 gray min/max partials ----
  {
    float2 a = part[tid];
    float mn = a.x, mx = a.y;
#pragma unroll
    for (int o = 32; o > 0; o >>= 1) {
      mn = fminf(mn, __shfl_xor(mn, o, 64));
      mx = fmaxf(mx, __shfl_xor(mx, o, 64));
    }
    if (lane == 0) { sred[wid] = mn; sred[16 + wid] = mx; }
  }
  if (tid < 16) sconv[tid] = 1;  // "not converged" before first iteration
  __syncthreads();
  float gmin, gmax;
  {
    float mn = sred[0], mx = sred[16];
#pragma unroll
    for (int i = 1; i < 16; ++i) {
      mn = fminf(mn, sred[i]);
      mx = fmaxf(mx, sred[16 + i]);
    }
    gmin = mn; gmax = mx;
  }
  const float den = __fsub_rn(gmax, gmin);

  const int by = blockIdx.x >> 4, bx = blockIdx.x & 15;  // 16 x 16
  const int ty = wid * 10 + ly * 5;  // tile-local y of lane row 0
  const int tx = lx * 5;             // tile-local x of lane col 0
  const int gy0 = by * COREY - HALO + ty;
  const int gx0 = bx * COREX - HALO + tx;

  float d[25], g[25], l[25];  // idx = r*5 + c, r in [0,5), c in [0,5)

  // ---------------- load + normalize + markers ----------------
#pragma unroll
  for (int r = 0; r < 5; ++r) {
    int gy = gy0 + r;
    bool rowin = (gy >= 0) && (gy < HW);
#pragma unroll
    for (int c = 0; c < 5; ++c) {
      int gx = gx0 + c;
      if (rowin && gx >= 0 && gx < HW) {
        float gv = __fdiv_rn(__fsub_rn(graw[(size_t)gy * HW + gx], gmin), den);
        g[r * 5 + c] = gv;
        bool s1 = gv < 0.3f, s2 = gv > 0.7f;
        d[r * 5 + c] = (s1 || s2) ? 0.0f : INFV;
        l[r * 5 + c] = s1 ? 1.0f : (s2 ? 2.0f : 0.0f);
      } else {
        g[r * 5 + c] = INFV;
        d[r * 5 + c] = INFV;
        l[r * 5 + c] = 0.0f;
      }
    }
  }

  // ---------------- iterate (Jacobi per direction, directions sequential) ---
#pragma unroll 1
  for (int it = 0; it < ITERS; ++it) {
    // publish pre-sweep bottom px-row of this wave (for DOWN of wave below)
    if (ly == 1) {
#pragma unroll
      for (int c = 0; c < 5; ++c) {
        Ebd[wid][lx * 5 + c] = d[20 + c];
        Ebl[wid][lx * 5 + c] = l[20 + c];
      }
    }
    __syncthreads();  // B1 (also publishes sconv from previous iteration)

    // early exit: previous full 4-dir pass made zero strict updates in the
    // whole tile -> fixed point; all later iterations are identities.
    {
      int s = 0;
#pragma unroll
      for (int i = 0; i < 16; ++i) s |= sconv[i];
      if (s == 0) break;
    }
    int anyU = 0;  // per-lane update accumulator (register)

    // ---- DOWN (candidate from row above, pre-pass values) ----
    {
      float pd[5], pl[5];
#pragma unroll
      for (int c = 0; c < 5; ++c) {
        pd[c] = __shfl_up(d[20 + c], 32, 64);
        pl[c] = __shfl_up(l[20 + c], 32, 64);
      }
      if (ly == 0) {
        if (wid == 0) {
#pragma unroll
          for (int c = 0; c < 5; ++c) { pd[c] = INFV; pl[c] = 0.0f; }
        } else {
#pragma unroll
          for (int c = 0; c < 5; ++c) {
            pd[c] = Ebd[wid - 1][lx * 5 + c];
            pl[c] = Ebl[wid - 1][lx * 5 + c];
          }
        }
      }
      // rows 4..1 in place: row r-1 still pre-pass
#pragma unroll
      for (int r = 4; r >= 1; --r) {
#pragma unroll
        for (int c = 0; c < 5; ++c) {
          float cur = d[r * 5 + c];
          float cand = (d[(r - 1) * 5 + c] + g[r * 5 + c]) + 1.0f;
          bool upd = cand < cur;
          d[r * 5 + c] = upd ? cand : cur;
          l[r * 5 + c] = upd ? l[(r - 1) * 5 + c] : l[r * 5 + c];
          anyU = upd ? 1 : anyU;
        }
      }
#pragma unroll
      for (int c = 0; c < 5; ++c) {
        float cur = d[c];
        float cand = (pd[c] + g[c]) + 1.0f;
        bool upd = cand < cur;
        d[c] = upd ? cand : cur;
        l[c] = upd ? pl[c] : l[c];
        anyU = upd ? 1 : anyU;
      }
      if (ly == 0) {  // post-DOWN top row (for UP of wave above)
#pragma unroll
        for (int c = 0; c < 5; ++c) {
          Etd[wid][lx * 5 + c] = d[c];
          Etl[wid][lx * 5 + c] = l[c];
        }
      }
    }
    __syncthreads();  // B2

    // ---- UP (candidate from row below, post-DOWN values) ----
    {
      float pd[5], pl[5];
#pragma unroll
      for (int c = 0; c < 5; ++c) {
        pd[c] = __shfl_down(d[c], 32, 64);
        pl[c] = __shfl_down(l[c], 32, 64);
      }
      if (ly == 1) {
        if (wid == 15) {
#pragma unroll
          for (int c = 0; c < 5; ++c) { pd[c] = INFV; pl[c] = 0.0f; }
        } else {
#pragma unroll
          for (int c = 0; c < 5; ++c) {
            pd[c] = Etd[wid + 1][lx * 5 + c];
            pl[c] = Etl[wid + 1][lx * 5 + c];
          }
        }
      }
#pragma unroll
      for (int r = 0; r <= 3; ++r) {
#pragma unroll
        for (int c = 0; c < 5; ++c) {
          float cur = d[r * 5 + c];
          float cand = (d[(r + 1) * 5 + c] + g[r * 5 + c]) + 1.0f;
          bool upd = cand < cur;
          d[r * 5 + c] = upd ? cand : cur;
          l[r * 5 + c] = upd ? l[(r + 1) * 5 + c] : l[r * 5 + c];
          anyU = upd ? 1 : anyU;
        }
      }
#pragma unroll
      for (int c = 0; c < 5; ++c) {
        float cur = d[20 + c];
        float cand = (pd[c] + g[20 + c]) + 1.0f;
        bool upd = cand < cur;
        d[20 + c] = upd ? cand : cur;
        l[20 + c] = upd ? pl[c] : l[20 + c];
        anyU = upd ? 1 : anyU;
      }
    }
    // no barrier: RIGHT/LEFT are purely intra-wave (wave spans full width)

    // ---- RIGHT (candidate from col left, post-UP values) ----
    {
      float pc[5], plc[5];
#pragma unroll
      for (int r = 0; r < 5; ++r) {
        pc[r] = __shfl_up(d[r * 5 + 4], 1, 64);
        plc[r] = __shfl_up(l[r * 5 + 4], 1, 64);
      }
      if (lx == 0) {  // tile-left edge (also masks the lane32<-31 wrap)
#pragma unroll
        for (int r = 0; r < 5; ++r) { pc[r] = INFV; plc[r] = 0.0f; }
      }
#pragma unroll
      for (int c = 4; c >= 1; --c) {
#pragma unroll
        for (int r = 0; r < 5; ++r) {
          float cur = d[r * 5 + c];
          float cand = (d[r * 5 + c - 1] + g[r * 5 + c]) + 1.0f;
          bool upd = cand < cur;
          d[r * 5 + c] = upd ? cand : cur;
          l[r * 5 + c] = upd ? l[r * 5 + c - 1] : l[r * 5 + c];
          anyU = upd ? 1 : anyU;
        }
      }
#pragma unroll
      for (int r = 0; r < 5; ++r) {
        float cur = d[r * 5];
        float cand = (pc[r] + g[r * 5]) + 1.0f;
        bool upd = cand < cur;
        d[r * 5] = upd ? cand : cur;
        l[r * 5] = upd ? plc[r] : l[r * 5];
        anyU = upd ? 1 : anyU;
      }
    }

    // ---- LEFT (candidate from col right, post-RIGHT values) ----
    {
      float pc[5], plc[5];
#pragma unroll
      for (int r = 0; r < 5; ++r) {
        pc[r] = __shfl_down(d[r * 5], 1, 64);
        plc[r] = __shfl_down(l[r * 5], 1, 64);
      }
      if (lx == 31) {  // tile-right edge (also masks the lane31<-32 wrap)
#pragma unroll
        for (int r = 0; r < 5; ++r) { pc[r] = INFV; plc[r] = 0.0f; }
      }
#pragma unroll
      for (int c = 0; c <= 3; ++c) {
#pragma unroll
        for (int r = 0; r < 5; ++r) {
          float cur = d[r * 5 + c];
          float cand = (d[r * 5 + c + 1] + g[r * 5 + c]) + 1.0f;
          bool upd = cand < cur;
          d[r * 5 + c] = upd ? cand : cur;
          l[r * 5 + c] = upd ? l[r * 5 + c + 1] : l[r * 5 + c];
          anyU = upd ? 1 : anyU;
        }
      }
#pragma unroll
      for (int r = 0; r < 5; ++r) {
        float cur = d[r * 5 + 4];
        float cand = (pc[r] + g[r * 5 + 4]) + 1.0f;
        bool upd = cand < cur;
        d[r * 5 + 4] = upd ? cand : cur;
        l[r * 5 + 4] = upd ? plc[r] : l[r * 5 + 4];
        anyU = upd ? 1 : anyU;
      }
    }

    // publish this iteration's per-wave convergence flag (one __any per
    // ITERATION); next B1 makes it visible to all waves.
    {
      int wany = __any(anyU);
      if (lane == 0) sconv[wid] = wany;
    }
    // no trailing barrier: next iteration's B1 covers the Ebd/sconv hazard
  }

  // ---------------- epilogue: stage label bytes, write float out ----------
#pragma unroll
  for (int r = 0; r < 5; ++r) {
#pragma unroll
    for (int c = 0; c < 5; ++c) {
      stagebuf[(ty + r) * TILEX + tx + c] = (uint8_t)l[r * 5 + c];
    }
  }
  __syncthreads();

  // labels at fixed point are in {1,2} (validated R4) -> out = label - 1
  const uint32_t* sb32 = (const uint32_t*)stagebuf;
#pragma unroll
  for (int k = 0; k < 4; ++k) {
    int j = tid + k * 1024;  // 0..4095 float4s of the 128x128 core
    int y = j >> 5;          // 32 float4 per core row
    int xq = j & 31;
    uint32_t v = sb32[(HALO + y) * (TILEX / 4) + (HALO / 4) + xq];
    float4 o;
    o.x = (float)(v & 0xFFu) - 1.0f;
    o.y = (float)((v >> 8) & 0xFFu) - 1.0f;
    o.z = (float)((v >> 16) & 0xFFu) - 1.0f;
    o.w = (float)(v >> 24) - 1.0f;
    *(float4*)(out + (size_t)(by * COREY + y) * HW + bx * COREX + xq * 4) = o;
  }
}

extern "C" void kernel_launch(void* const* d_in, const int* in_sizes, int n_in,
                              void* d_out, int out_size, void* d_ws, size_t ws_size,
                              hipStream_t stream) {
  const float* img = (const float*)d_in[0];
  float* out = (float*)d_out;
  char* ws = (char*)d_ws;

  float2* part = (float2*)ws;            // 8 KB (1024 float2)
  float* graw = (float*)(ws + 16384);    // 16.8 MB

  k_stage1<<<1024, 256, 0, stream>>>(img, graw, part);
  k_sweep<<<NBLK, 1024, 0, stream>>>(graw, part, out);
}

// Round 7
// 128.025 us; speedup vs baseline: 1.2273x; 1.0601x over previous
//
#include <hip/hip_runtime.h>
#include <stdint.h>

// WatershedFilter on MI355X — v12.
// R11 post-mortem (v11 1024-thr, k_sweep 53.0 us, bench 135.7 = best):
// WIN. Occupancy 16->31%, but mild spill returned (WRITE 16.4->27.9 MB:
// ~115 live floats vs 128 unified regs/wave at 4 waves/SIMD) and
// VALUBusy dropped to 42% (spill latency ate part of the TLP gain).
// Structure ladder is in diminishing returns; time = per-iter cost x ~11
// effective iterations.
// v12 = cut ITERATION COUNT: Gauss-Seidel inside the lane's 5x5 block.
//  - Fact: the min-plus relax operator has a UNIQUE fixed point
//    independent of schedule (monotone non-increasing; every d is an
//    exact stepwise path-sum; fixed point = min over path-sums). Labels
//    follow strict argmin; ties between float path-sums ~measure 0.
//    Evidence: v5/v8/v10/v11 each changed the schedule, all absmax 0.
//  - Change: each direction pass relaxes the boundary row/col FIRST
//    (from pre-pass neighbor via shfl/LDS, protocol unchanged), then
//    sweeps FORWARD reading UPDATED in-lane values (G-S). A monotone
//    run of <=5 px completes in 1 pass instead of 5. G-S dominates
//    Jacobi pointwise -> converges no slower; expect ~4-6 iters instead
//    of ~10-11. Early exit harvests automatically. Same inst count/pass.
//  - ITERS=12 stays as safety bound (G-S <= Jacobi per iter; Jacobi@12
//    validated exact). If absmax != 0: ties matter -> revert to v11.
// Geometry (= v11): 16 waves stacked vertically, wave = 10 rows x 160
// cols, lanes 2x32, lane = 5x5 px; tile 160x160, core 128x128, halo 16;
// grid 16x16 = 256 blocks = 1/CU. 2 barriers/iter (B1: Ebd pre-pass
// bottom rows + sconv consensus; B2: Etd post-DOWN top rows).
// RIGHT/LEFT intra-wave (shfl by 1, lx edge-masked).
// Exactness anchors (validated): gray via __fmul_rn/__fadd_rn in numpy
// order; normalize __fdiv_rn(__fsub_rn(v,gmin), fl(gmax-gmin));
// cand=(nd+gray)+1.0f left-assoc; strict '<'; out-of-image px get
// g=d=1e9 pinning dist at exactly 1e9 == reference INF fill; labels at
// fixed point in {1,2} -> out = label - 1.0f.

#define HW    2048
#define N2    (HW * HW)
#define INFV  1e9f
#define TILEY 160
#define TILEX 160
#define COREY 128
#define COREX 128
#define HALO  16
#define NBLK  256
#define ITERS 12

// Stage 1: raw gray -> graw, block min/max -> part[block]. 1024 blocks.
__global__ __launch_bounds__(256) void k_stage1(const float* __restrict__ img,
                                                float* __restrict__ graw,
                                                float2* __restrict__ part) {
  const float4* R = (const float4*)img;
  const float4* G = (const float4*)(img + N2);
  const float4* B = (const float4*)(img + 2 * N2);
  float4* O = (float4*)graw;
  float mn = INFV, mx = 0.0f;
  int base = blockIdx.x * 256 + threadIdx.x;
#pragma unroll
  for (int k = 0; k < 4; ++k) {
    int j = base + k * (1024 * 256);  // N2/4 = 1048576 = 4 * 262144 exact
    float4 r = R[j], g = G[j], b = B[j];
    float4 o;
    o.x = __fadd_rn(__fadd_rn(__fmul_rn(0.2989f, r.x), __fmul_rn(0.587f, g.x)),
                    __fmul_rn(0.114f, b.x));
    o.y = __fadd_rn(__fadd_rn(__fmul_rn(0.2989f, r.y), __fmul_rn(0.587f, g.y)),
                    __fmul_rn(0.114f, b.y));
    o.z = __fadd_rn(__fadd_rn(__fmul_rn(0.2989f, r.z), __fmul_rn(0.587f, g.z)),
                    __fmul_rn(0.114f, b.z));
    o.w = __fadd_rn(__fadd_rn(__fmul_rn(0.2989f, r.w), __fmul_rn(0.587f, g.w)),
                    __fmul_rn(0.114f, b.w));
    O[j] = o;
    mn = fminf(mn, fminf(fminf(o.x, o.y), fminf(o.z, o.w)));
    mx = fmaxf(mx, fmaxf(fmaxf(o.x, o.y), fmaxf(o.z, o.w)));
  }
#pragma unroll
  for (int o = 32; o > 0; o >>= 1) {
    mn = fminf(mn, __shfl_xor(mn, o, 64));
    mx = fmaxf(mx, __shfl_xor(mx, o, 64));
  }
  __shared__ float smn[4], smx[4];
  int wid = threadIdx.x >> 6;
  if ((threadIdx.x & 63) == 0) { smn[wid] = mn; smx[wid] = mx; }
  __syncthreads();
  if (threadIdx.x == 0) {
    mn = fminf(fminf(smn[0], smn[1]), fminf(smn[2], smn[3]));
    mx = fmaxf(fmaxf(smx[0], smx[1]), fmaxf(smx[2], smx[3]));
    part[blockIdx.x] = make_float2(mn, mx);
  }
}

__global__ __launch_bounds__(1024, 2) void k_sweep(
    const float* __restrict__ graw, const float2* __restrict__ part,
    float* __restrict__ out) {
  // vertical inter-wave edge buffers only (waves span full tile width)
  __shared__ float Ebd[16][160], Ebl[16][160];  // pre-pass bottom rows
  __shared__ float Etd[16][160], Etl[16][160];  // post-DOWN top rows
  __shared__ float sred[32];
  __shared__ int sconv[16];  // per-wave "any strict update last iteration"
  __shared__ uint8_t stagebuf[TILEY * TILEX];  // 25600 B

  const int tid = threadIdx.x;
  const int wid = tid >> 6;   // 0..15, stacked vertically (wid 0 = top)
  const int lane = tid & 63;
  const int ly = lane >> 5;   // 0..1 lane-rows within wave
  const int lx = lane & 31;   // 0..31 lane-cols (full tile width)

  // ---- prologue: reduce 1024 gray min/max partials ----
  {
    float2 a = part[tid];
    float mn = a.x, mx = a.y;
#pragma unroll
    for (int o = 32; o > 0; o >>= 1) {
      mn = fminf(mn, __shfl_xor(mn, o, 64));
      mx = fmaxf(mx, __shfl_xor(mx, o, 64));
    }
    if (lane == 0) { sred[wid] = mn; sred[16 + wid] = mx; }
  }
  if (tid < 16) sconv[tid] = 1;  // "not converged" before first iteration
  __syncthreads();
  float gmin, gmax;
  {
    float mn = sred[0], mx = sred[16];
#pragma unroll
    for (int i = 1; i < 16; ++i) {
      mn = fminf(mn, sred[i]);
      mx = fmaxf(mx, sred[16 + i]);
    }
    gmin = mn; gmax = mx;
  }
  const float den = __fsub_rn(gmax, gmin);

  const int by = blockIdx.x >> 4, bx = blockIdx.x & 15;  // 16 x 16
  const int ty = wid * 10 + ly * 5;  // tile-local y of lane row 0
  const int tx = lx * 5;             // tile-local x of lane col 0
  const int gy0 = by * COREY - HALO + ty;
  const int gx0 = bx * COREX - HALO + tx;

  float d[25], g[25], l[25];  // idx = r*5 + c, r in [0,5), c in [0,5)

  // ---------------- load + normalize + markers ----------------
#pragma unroll
  for (int r = 0; r < 5; ++r) {
    int gy = gy0 + r;
    bool rowin = (gy >= 0) && (gy < HW);
#pragma unroll
    for (int c = 0; c < 5; ++c) {
      int gx = gx0 + c;
      if (rowin && gx >= 0 && gx < HW) {
        float gv = __fdiv_rn(__fsub_rn(graw[(size_t)gy * HW + gx], gmin), den);
        g[r * 5 + c] = gv;
        bool s1 = gv < 0.3f, s2 = gv > 0.7f;
        d[r * 5 + c] = (s1 || s2) ? 0.0f : INFV;
        l[r * 5 + c] = s1 ? 1.0f : (s2 ? 2.0f : 0.0f);
      } else {
        g[r * 5 + c] = INFV;
        d[r * 5 + c] = INFV;
        l[r * 5 + c] = 0.0f;
      }
    }
  }

  // ---------------- iterate (G-S within lane, Jacobi across lanes) --------
#pragma unroll 1
  for (int it = 0; it < ITERS; ++it) {
    // publish pre-sweep bottom px-row of this wave (for DOWN of wave below)
    if (ly == 1) {
#pragma unroll
      for (int c = 0; c < 5; ++c) {
        Ebd[wid][lx * 5 + c] = d[20 + c];
        Ebl[wid][lx * 5 + c] = l[20 + c];
      }
    }
    __syncthreads();  // B1 (also publishes sconv from previous iteration)

    // early exit: previous full 4-dir pass made zero strict updates in the
    // whole tile -> fixed point; all later iterations are identities.
    {
      int s = 0;
#pragma unroll
      for (int i = 0; i < 16; ++i) s |= sconv[i];
      if (s == 0) break;
    }
    int anyU = 0;  // per-lane update accumulator (register)

    // ---- DOWN (boundary row first, then G-S forward: r-1 updated) ----
    {
      float pd[5], pl[5];
#pragma unroll
      for (int c = 0; c < 5; ++c) {
        pd[c] = __shfl_up(d[20 + c], 32, 64);
        pl[c] = __shfl_up(l[20 + c], 32, 64);
      }
      if (ly == 0) {
        if (wid == 0) {
#pragma unroll
          for (int c = 0; c < 5; ++c) { pd[c] = INFV; pl[c] = 0.0f; }
        } else {
#pragma unroll
          for (int c = 0; c < 5; ++c) {
            pd[c] = Ebd[wid - 1][lx * 5 + c];
            pl[c] = Ebl[wid - 1][lx * 5 + c];
          }
        }
      }
      // row 0 from cross-boundary neighbor (pre-pass, protocol unchanged)
#pragma unroll
      for (int c = 0; c < 5; ++c) {
        float cur = d[c];
        float cand = (pd[c] + g[c]) + 1.0f;
        bool upd = cand < cur;
        d[c] = upd ? cand : cur;
        l[c] = upd ? pl[c] : l[c];
        anyU = upd ? 1 : anyU;
      }
      // rows 1..4 Gauss-Seidel: row r-1 already updated this pass
#pragma unroll
      for (int r = 1; r <= 4; ++r) {
#pragma unroll
        for (int c = 0; c < 5; ++c) {
          float cur = d[r * 5 + c];
          float cand = (d[(r - 1) * 5 + c] + g[r * 5 + c]) + 1.0f;
          bool upd = cand < cur;
          d[r * 5 + c] = upd ? cand : cur;
          l[r * 5 + c] = upd ? l[(r - 1) * 5 + c] : l[r * 5 + c];
          anyU = upd ? 1 : anyU;
        }
      }
      if (ly == 0) {  // post-DOWN top row (for UP of wave above)
#pragma unroll
        for (int c = 0; c < 5; ++c) {
          Etd[wid][lx * 5 + c] = d[c];
          Etl[wid][lx * 5 + c] = l[c];
        }
      }
    }
    __syncthreads();  // B2

    // ---- UP (boundary row first, then G-S backward: r+1 updated) ----
    {
      float pd[5], pl[5];
#pragma unroll
      for (int c = 0; c < 5; ++c) {
        pd[c] = __shfl_down(d[c], 32, 64);
        pl[c] = __shfl_down(l[c], 32, 64);
      }
      if (ly == 1) {
        if (wid == 15) {
#pragma unroll
          for (int c = 0; c < 5; ++c) { pd[c] = INFV; pl[c] = 0.0f; }
        } else {
#pragma unroll
          for (int c = 0; c < 5; ++c) {
            pd[c] = Etd[wid + 1][lx * 5 + c];
            pl[c] = Etl[wid + 1][lx * 5 + c];
          }
        }
      }
      // row 4 from cross-boundary neighbor (pre-pass)
#pragma unroll
      for (int c = 0; c < 5; ++c) {
        float cur = d[20 + c];
        float cand = (pd[c] + g[20 + c]) + 1.0f;
        bool upd = cand < cur;
        d[20 + c] = upd ? cand : cur;
        l[20 + c] = upd ? pl[c] : l[20 + c];
        anyU = upd ? 1 : anyU;
      }
      // rows 3..0 Gauss-Seidel: row r+1 already updated this pass
#pragma unroll
      for (int r = 3; r >= 0; --r) {
#pragma unroll
        for (int c = 0; c < 5; ++c) {
          float cur = d[r * 5 + c];
          float cand = (d[(r + 1) * 5 + c] + g[r * 5 + c]) + 1.0f;
          bool upd = cand < cur;
          d[r * 5 + c] = upd ? cand : cur;
          l[r * 5 + c] = upd ? l[(r + 1) * 5 + c] : l[r * 5 + c];
          anyU = upd ? 1 : anyU;
        }
      }
    }
    // no barrier: RIGHT/LEFT are purely intra-wave (wave spans full width)

    // ---- RIGHT (boundary col first, then G-S forward: c-1 updated) ----
    {
      float pc[5], plc[5];
#pragma unroll
      for (int r = 0; r < 5; ++r) {
        pc[r] = __shfl_up(d[r * 5 + 4], 1, 64);
        plc[r] = __shfl_up(l[r * 5 + 4], 1, 64);
      }
      if (lx == 0) {  // tile-left edge (also masks the lane32<-31 wrap)
#pragma unroll
        for (int r = 0; r < 5; ++r) { pc[r] = INFV; plc[r] = 0.0f; }
      }
      // col 0 from left-lane neighbor (pre-pass)
#pragma unroll
      for (int r = 0; r < 5; ++r) {
        float cur = d[r * 5];
        float cand = (pc[r] + g[r * 5]) + 1.0f;
        bool upd = cand < cur;
        d[r * 5] = upd ? cand : cur;
        l[r * 5] = upd ? plc[r] : l[r * 5];
        anyU = upd ? 1 : anyU;
      }
      // cols 1..4 Gauss-Seidel: col c-1 already updated this pass
#pragma unroll
      for (int c = 1; c <= 4; ++c) {
#pragma unroll
        for (int r = 0; r < 5; ++r) {
          float cur = d[r * 5 + c];
          float cand = (d[r * 5 + c - 1] + g[r * 5 + c]) + 1.0f;
          bool upd = cand < cur;
          d[r * 5 + c] = upd ? cand : cur;
          l[r * 5 + c] = upd ? l[r * 5 + c - 1] : l[r * 5 + c];
          anyU = upd ? 1 : anyU;
        }
      }
    }

    // ---- LEFT (boundary col first, then G-S backward: c+1 updated) ----
    {
      float pc[5], plc[5];
#pragma unroll
      for (int r = 0; r < 5; ++r) {
        pc[r] = __shfl_down(d[r * 5], 1, 64);
        plc[r] = __shfl_down(l[r * 5], 1, 64);
      }
      if (lx == 31) {  // tile-right edge (also masks the lane31<-32 wrap)
#pragma unroll
        for (int r = 0; r < 5; ++r) { pc[r] = INFV; plc[r] = 0.0f; }
      }
      // col 4 from right-lane neighbor (pre-pass)
#pragma unroll
      for (int r = 0; r < 5; ++r) {
        float cur = d[r * 5 + 4];
        float cand = (pc[r] + g[r * 5 + 4]) + 1.0f;
        bool upd = cand < cur;
        d[r * 5 + 4] = upd ? cand : cur;
        l[r * 5 + 4] = upd ? plc[r] : l[r * 5 + 4];
        anyU = upd ? 1 : anyU;
      }
      // cols 3..0 Gauss-Seidel: col c+1 already updated this pass
#pragma unroll
      for (int c = 3; c >= 0; --c) {
#pragma unroll
        for (int r = 0; r < 5; ++r) {
          float cur = d[r * 5 + c];
          float cand = (d[r * 5 + c + 1] + g[r * 5 + c]) + 1.0f;
          bool upd = cand < cur;
          d[r * 5 + c] = upd ? cand : cur;
          l[r * 5 + c] = upd ? l[r * 5 + c + 1] : l[r * 5 + c];
          anyU = upd ? 1 : anyU;
        }
      }
    }

    // publish this iteration's per-wave convergence flag (one __any per
    // ITERATION); next B1 makes it visible to all waves.
    {
      int wany = __any(anyU);
      if (lane == 0) sconv[wid] = wany;
    }
    // no trailing barrier: next iteration's B1 covers the Ebd/sconv hazard
  }

  // ---------------- epilogue: stage label bytes, write float out ----------
#pragma unroll
  for (int r = 0; r < 5; ++r) {
#pragma unroll
    for (int c = 0; c < 5; ++c) {
      stagebuf[(ty + r) * TILEX + tx + c] = (uint8_t)l[r * 5 + c];
    }
  }
  __syncthreads();

  // labels at fixed point are in {1,2} (validated R4) -> out = label - 1
  const uint32_t* sb32 = (const uint32_t*)stagebuf;
#pragma unroll
  for (int k = 0; k < 4; ++k) {
    int j = tid + k * 1024;  // 0..4095 float4s of the 128x128 core
    int y = j >> 5;          // 32 float4 per core row
    int xq = j & 31;
    uint32_t v = sb32[(HALO + y) * (TILEX / 4) + (HALO / 4) + xq];
    float4 o;
    o.x = (float)(v & 0xFFu) - 1.0f;
    o.y = (float)((v >> 8) & 0xFFu) - 1.0f;
    o.z = (float)((v >> 16) & 0xFFu) - 1.0f;
    o.w = (float)(v >> 24) - 1.0f;
    *(float4*)(out + (size_t)(by * COREY + y) * HW + bx * COREX + xq * 4) = o;
  }
}

extern "C" void kernel_launch(void* const* d_in, const int* in_sizes, int n_in,
                              void* d_out, int out_size, void* d_ws, size_t ws_size,
                              hipStream_t stream) {
  const float* img = (const float*)d_in[0];
  float* out = (float*)d_out;
  char* ws = (char*)d_ws;

  float2* part = (float2*)ws;            // 8 KB (1024 float2)
  float* graw = (float*)(ws + 16384);    // 16.8 MB

  k_stage1<<<1024, 256, 0, stream>>>(img, graw, part);
  k_sweep<<<NBLK, 1024, 0, stream>>>(graw, part, out);
}

// Round 8
// 125.762 us; speedup vs baseline: 1.2494x; 1.0180x over previous
//
#include <hip/hip_runtime.h>
#include <stdint.h>

// WatershedFilter on MI355X — v13.
// R12 post-mortem (v12 G-S, k_sweep 45.8 us, bench 128.0 = best): WIN.
// Iters ~9.3 (from ~11), per-iter ~4.3 us, busy 53%. Cycle accounting
// closes: busy cyc/SIMD ~59K == source inst x 2cyc x 4 waves. Remaining
// cost: every wave pays all ~9.3 iterations though most of the tile
// converges by ~5; and 47% stall (shfl/barrier/scratch).
// v13 = v12 + PENTA-GROUP WAVE SKIPPING:
//  - Cross-wave dataflow is ONLY vertical (Ebd/Etd; RIGHT/LEFT are
//    intra-wave). A wave w with sconv[w-2..w+2] all 0 last iteration
//    provably cannot update this iteration: own state unchanged,
//    Ebd[w-1] unchanged, and Etd[w+1] unchanged because w+1 is itself
//    inactive (its tri-group within w's penta-group). Tri-group alone is
//    INSUFFICIENT (w+1 could be re-activated by w+2 and change its
//    post-DOWN top row mid-iteration). Skip = value-level no-op ->
//    absmax 0 by construction; all-zero exit still implies fixed point.
//  - Inactive waves: publish Ebd (cheap, keeps LDS = current values),
//    hit B1/B2 unconditionally (no barrier divergence), skip the 4
//    relax passes + flag write (their sconv is already 0).
//  - Expect ~4-5 full-active iterations then fast-shrinking active set
//    over the ~4-5 tail iterations; stragglers also get more issue BW.
//  - TRIPWIRE: WRITE_SIZE >> 21.5 MB = regalloc perturbed -> revert.
// Geometry (= v12): 16 waves stacked vertically, wave = 10 rows x 160
// cols, lanes 2x32, lane = 5x5 px G-S; tile 160x160, core 128x128,
// halo 16; grid 16x16 = 256 blocks = 1/CU; 2 barriers/iter.
// Exactness anchors (validated v5..v12, absmax 0): gray via __fmul_rn/
// __fadd_rn in numpy order; normalize __fdiv_rn(__fsub_rn(v,gmin),
// fl(gmax-gmin)); cand=(nd+gray)+1.0f left-assoc; strict '<'; INF px
// pinned at exactly 1e9; unique fixed point independent of schedule
// (6 schedule changes, all absmax 0); labels in {1,2} -> out = label-1.

#define HW    2048
#define N2    (HW * HW)
#define INFV  1e9f
#define TILEY 160
#define TILEX 160
#define COREY 128
#define COREX 128
#define HALO  16
#define NBLK  256
#define ITERS 12

// Stage 1: raw gray -> graw, block min/max -> part[block]. 1024 blocks.
__global__ __launch_bounds__(256) void k_stage1(const float* __restrict__ img,
                                                float* __restrict__ graw,
                                                float2* __restrict__ part) {
  const float4* R = (const float4*)img;
  const float4* G = (const float4*)(img + N2);
  const float4* B = (const float4*)(img + 2 * N2);
  float4* O = (float4*)graw;
  float mn = INFV, mx = 0.0f;
  int base = blockIdx.x * 256 + threadIdx.x;
#pragma unroll
  for (int k = 0; k < 4; ++k) {
    int j = base + k * (1024 * 256);  // N2/4 = 1048576 = 4 * 262144 exact
    float4 r = R[j], g = G[j], b = B[j];
    float4 o;
    o.x = __fadd_rn(__fadd_rn(__fmul_rn(0.2989f, r.x), __fmul_rn(0.587f, g.x)),
                    __fmul_rn(0.114f, b.x));
    o.y = __fadd_rn(__fadd_rn(__fmul_rn(0.2989f, r.y), __fmul_rn(0.587f, g.y)),
                    __fmul_rn(0.114f, b.y));
    o.z = __fadd_rn(__fadd_rn(__fmul_rn(0.2989f, r.z), __fmul_rn(0.587f, g.z)),
                    __fmul_rn(0.114f, b.z));
    o.w = __fadd_rn(__fadd_rn(__fmul_rn(0.2989f, r.w), __fmul_rn(0.587f, g.w)),
                    __fmul_rn(0.114f, b.w));
    O[j] = o;
    mn = fminf(mn, fminf(fminf(o.x, o.y), fminf(o.z, o.w)));
    mx = fmaxf(mx, fmaxf(fmaxf(o.x, o.y), fmaxf(o.z, o.w)));
  }
#pragma unroll
  for (int o = 32; o > 0; o >>= 1) {
    mn = fminf(mn, __shfl_xor(mn, o, 64));
    mx = fmaxf(mx, __shfl_xor(mx, o, 64));
  }
  __shared__ float smn[4], smx[4];
  int wid = threadIdx.x >> 6;
  if ((threadIdx.x & 63) == 0) { smn[wid] = mn; smx[wid] = mx; }
  __syncthreads();
  if (threadIdx.x == 0) {
    mn = fminf(fminf(smn[0], smn[1]), fminf(smn[2], smn[3]));
    mx = fmaxf(fmaxf(smx[0], smx[1]), fmaxf(smx[2], smx[3]));
    part[blockIdx.x] = make_float2(mn, mx);
  }
}

__global__ __launch_bounds__(1024, 2) void k_sweep(
    const float* __restrict__ graw, const float2* __restrict__ part,
    float* __restrict__ out) {
  // vertical inter-wave edge buffers only (waves span full tile width)
  __shared__ float Ebd[16][160], Ebl[16][160];  // pre-pass bottom rows
  __shared__ float Etd[16][160], Etl[16][160];  // post-DOWN top rows
  __shared__ float sred[32];
  __shared__ int sconv[16];  // per-wave "any strict update last iteration"
  __shared__ uint8_t stagebuf[TILEY * TILEX];  // 25600 B

  const int tid = threadIdx.x;
  const int wid = tid >> 6;   // 0..15, stacked vertically (wid 0 = top)
  const int lane = tid & 63;
  const int ly = lane >> 5;   // 0..1 lane-rows within wave
  const int lx = lane & 31;   // 0..31 lane-cols (full tile width)

  // ---- prologue: reduce 1024 gray min/max partials ----
  {
    float2 a = part[tid];
    float mn = a.x, mx = a.y;
#pragma unroll
    for (int o = 32; o > 0; o >>= 1) {
      mn = fminf(mn, __shfl_xor(mn, o, 64));
      mx = fmaxf(mx, __shfl_xor(mx, o, 64));
    }
    if (lane == 0) { sred[wid] = mn; sred[16 + wid] = mx; }
  }
  if (tid < 16) sconv[tid] = 1;  // "not converged" before first iteration
  __syncthreads();
  float gmin, gmax;
  {
    float mn = sred[0], mx = sred[16];
#pragma unroll
    for (int i = 1; i < 16; ++i) {
      mn = fminf(mn, sred[i]);
      mx = fmaxf(mx, sred[16 + i]);
    }
    gmin = mn; gmax = mx;
  }
  const float den = __fsub_rn(gmax, gmin);

  const int by = blockIdx.x >> 4, bx = blockIdx.x & 15;  // 16 x 16
  const int ty = wid * 10 + ly * 5;  // tile-local y of lane row 0
  const int tx = lx * 5;             // tile-local x of lane col 0
  const int gy0 = by * COREY - HALO + ty;
  const int gx0 = bx * COREX - HALO + tx;

  float d[25], g[25], l[25];  // idx = r*5 + c, r in [0,5), c in [0,5)

  // ---------------- load + normalize + markers ----------------
#pragma unroll
  for (int r = 0; r < 5; ++r) {
    int gy = gy0 + r;
    bool rowin = (gy >= 0) && (gy < HW);
#pragma unroll
    for (int c = 0; c < 5; ++c) {
      int gx = gx0 + c;
      if (rowin && gx >= 0 && gx < HW) {
        float gv = __fdiv_rn(__fsub_rn(graw[(size_t)gy * HW + gx], gmin), den);
        g[r * 5 + c] = gv;
        bool s1 = gv < 0.3f, s2 = gv > 0.7f;
        d[r * 5 + c] = (s1 || s2) ? 0.0f : INFV;
        l[r * 5 + c] = s1 ? 1.0f : (s2 ? 2.0f : 0.0f);
      } else {
        g[r * 5 + c] = INFV;
        d[r * 5 + c] = INFV;
        l[r * 5 + c] = 0.0f;
      }
    }
  }

  // ---------------- iterate (G-S within lane, Jacobi across lanes) --------
#pragma unroll 1
  for (int it = 0; it < ITERS; ++it) {
    // publish pre-sweep bottom px-row of this wave (for DOWN of wave below);
    // unconditional: inactive waves republish unchanged values (cheap).
    if (ly == 1) {
#pragma unroll
      for (int c = 0; c < 5; ++c) {
        Ebd[wid][lx * 5 + c] = d[20 + c];
        Ebl[wid][lx * 5 + c] = l[20 + c];
      }
    }
    __syncthreads();  // B1 (publishes sconv + Ebd from previous segment)

    // early exit: previous full 4-dir pass made zero strict updates in the
    // whole tile -> fixed point; all later iterations are identities.
    {
      int s = 0;
#pragma unroll
      for (int i = 0; i < 16; ++i) s |= sconv[i];
      if (s == 0) break;
    }
    // penta-group activity: wave w can update this iteration only if some
    // wave in {w-2..w+2} updated last iteration (see header proof).
    const int wm2 = wid < 2 ? 0 : wid - 2;
    const int wm1 = wid < 1 ? 0 : wid - 1;
    const int wp1 = wid > 14 ? 15 : wid + 1;
    const int wp2 = wid > 13 ? 15 : wid + 2;
    const int active =
        sconv[wm2] | sconv[wm1] | sconv[wid] | sconv[wp1] | sconv[wp2];
    int anyU = 0;  // per-lane update accumulator (register)

    if (active) {
      // ---- DOWN (boundary row first, then G-S forward: r-1 updated) ----
      float pd[5], pl[5];
#pragma unroll
      for (int c = 0; c < 5; ++c) {
        pd[c] = __shfl_up(d[20 + c], 32, 64);
        pl[c] = __shfl_up(l[20 + c], 32, 64);
      }
      if (ly == 0) {
        if (wid == 0) {
#pragma unroll
          for (int c = 0; c < 5; ++c) { pd[c] = INFV; pl[c] = 0.0f; }
        } else {
#pragma unroll
          for (int c = 0; c < 5; ++c) {
            pd[c] = Ebd[wid - 1][lx * 5 + c];
            pl[c] = Ebl[wid - 1][lx * 5 + c];
          }
        }
      }
      // row 0 from cross-boundary neighbor (pre-pass, protocol unchanged)
#pragma unroll
      for (int c = 0; c < 5; ++c) {
        float cur = d[c];
        float cand = (pd[c] + g[c]) + 1.0f;
        bool upd = cand < cur;
        d[c] = upd ? cand : cur;
        l[c] = upd ? pl[c] : l[c];
        anyU = upd ? 1 : anyU;
      }
      // rows 1..4 Gauss-Seidel: row r-1 already updated this pass
#pragma unroll
      for (int r = 1; r <= 4; ++r) {
#pragma unroll
        for (int c = 0; c < 5; ++c) {
          float cur = d[r * 5 + c];
          float cand = (d[(r - 1) * 5 + c] + g[r * 5 + c]) + 1.0f;
          bool upd = cand < cur;
          d[r * 5 + c] = upd ? cand : cur;
          l[r * 5 + c] = upd ? l[(r - 1) * 5 + c] : l[r * 5 + c];
          anyU = upd ? 1 : anyU;
        }
      }
      if (ly == 0) {  // post-DOWN top row (for UP of wave above)
#pragma unroll
        for (int c = 0; c < 5; ++c) {
          Etd[wid][lx * 5 + c] = d[c];
          Etl[wid][lx * 5 + c] = l[c];
        }
      }
    }
    __syncthreads();  // B2 (unconditional: no barrier divergence)

    if (active) {
      // ---- UP (boundary row first, then G-S backward: r+1 updated) ----
      {
        float pd[5], pl[5];
#pragma unroll
        for (int c = 0; c < 5; ++c) {
          pd[c] = __shfl_down(d[c], 32, 64);
          pl[c] = __shfl_down(l[c], 32, 64);
        }
        if (ly == 1) {
          if (wid == 15) {
#pragma unroll
            for (int c = 0; c < 5; ++c) { pd[c] = INFV; pl[c] = 0.0f; }
          } else {
#pragma unroll
            for (int c = 0; c < 5; ++c) {
              pd[c] = Etd[wid + 1][lx * 5 + c];
              pl[c] = Etl[wid + 1][lx * 5 + c];
            }
          }
        }
        // row 4 from cross-boundary neighbor (pre-pass)
#pragma unroll
        for (int c = 0; c < 5; ++c) {
          float cur = d[20 + c];
          float cand = (pd[c] + g[20 + c]) + 1.0f;
          bool upd = cand < cur;
          d[20 + c] = upd ? cand : cur;
          l[20 + c] = upd ? pl[c] : l[20 + c];
          anyU = upd ? 1 : anyU;
        }
        // rows 3..0 Gauss-Seidel: row r+1 already updated this pass
#pragma unroll
        for (int r = 3; r >= 0; --r) {
#pragma unroll
          for (int c = 0; c < 5; ++c) {
            float cur = d[r * 5 + c];
            float cand = (d[(r + 1) * 5 + c] + g[r * 5 + c]) + 1.0f;
            bool upd = cand < cur;
            d[r * 5 + c] = upd ? cand : cur;
            l[r * 5 + c] = upd ? l[(r + 1) * 5 + c] : l[r * 5 + c];
            anyU = upd ? 1 : anyU;
          }
        }
      }

      // ---- RIGHT (boundary col first, then G-S forward: c-1 updated) ----
      {
        float pc[5], plc[5];
#pragma unroll
        for (int r = 0; r < 5; ++r) {
          pc[r] = __shfl_up(d[r * 5 + 4], 1, 64);
          plc[r] = __shfl_up(l[r * 5 + 4], 1, 64);
        }
        if (lx == 0) {  // tile-left edge (also masks the lane32<-31 wrap)
#pragma unroll
          for (int r = 0; r < 5; ++r) { pc[r] = INFV; plc[r] = 0.0f; }
        }
        // col 0 from left-lane neighbor (pre-pass)
#pragma unroll
        for (int r = 0; r < 5; ++r) {
          float cur = d[r * 5];
          float cand = (pc[r] + g[r * 5]) + 1.0f;
          bool upd = cand < cur;
          d[r * 5] = upd ? cand : cur;
          l[r * 5] = upd ? plc[r] : l[r * 5];
          anyU = upd ? 1 : anyU;
        }
        // cols 1..4 Gauss-Seidel: col c-1 already updated this pass
#pragma unroll
        for (int c = 1; c <= 4; ++c) {
#pragma unroll
          for (int r = 0; r < 5; ++r) {
            float cur = d[r * 5 + c];
            float cand = (d[r * 5 + c - 1] + g[r * 5 + c]) + 1.0f;
            bool upd = cand < cur;
            d[r * 5 + c] = upd ? cand : cur;
            l[r * 5 + c] = upd ? l[r * 5 + c - 1] : l[r * 5 + c];
            anyU = upd ? 1 : anyU;
          }
        }
      }

      // ---- LEFT (boundary col first, then G-S backward: c+1 updated) ----
      {
        float pc[5], plc[5];
#pragma unroll
        for (int r = 0; r < 5; ++r) {
          pc[r] = __shfl_down(d[r * 5], 1, 64);
          plc[r] = __shfl_down(l[r * 5], 1, 64);
        }
        if (lx == 31) {  // tile-right edge (also masks the lane31<-32 wrap)
#pragma unroll
          for (int r = 0; r < 5; ++r) { pc[r] = INFV; plc[r] = 0.0f; }
        }
        // col 4 from right-lane neighbor (pre-pass)
#pragma unroll
        for (int r = 0; r < 5; ++r) {
          float cur = d[r * 5 + 4];
          float cand = (pc[r] + g[r * 5 + 4]) + 1.0f;
          bool upd = cand < cur;
          d[r * 5 + 4] = upd ? cand : cur;
          l[r * 5 + 4] = upd ? plc[r] : l[r * 5 + 4];
          anyU = upd ? 1 : anyU;
        }
        // cols 3..0 Gauss-Seidel: col c+1 already updated this pass
#pragma unroll
        for (int c = 3; c >= 0; --c) {
#pragma unroll
          for (int r = 0; r < 5; ++r) {
            float cur = d[r * 5 + c];
            float cand = (d[r * 5 + c + 1] + g[r * 5 + c]) + 1.0f;
            bool upd = cand < cur;
            d[r * 5 + c] = upd ? cand : cur;
            l[r * 5 + c] = upd ? l[r * 5 + c + 1] : l[r * 5 + c];
            anyU = upd ? 1 : anyU;
          }
        }
      }

      // publish this iteration's per-wave convergence flag; inactive waves
      // skip (their sconv is already 0). Next B1 makes it visible.
      {
        int wany = __any(anyU);
        if (lane == 0) sconv[wid] = wany;
      }
    }
    // no trailing barrier: next iteration's B1 covers the Ebd/sconv hazard
  }

  // ---------------- epilogue: stage label bytes, write float out ----------
#pragma unroll
  for (int r = 0; r < 5; ++r) {
#pragma unroll
    for (int c = 0; c < 5; ++c) {
      stagebuf[(ty + r) * TILEX + tx + c] = (uint8_t)l[r * 5 + c];
    }
  }
  __syncthreads();

  // labels at fixed point are in {1,2} (validated R4) -> out = label - 1
  const uint32_t* sb32 = (const uint32_t*)stagebuf;
#pragma unroll
  for (int k = 0; k < 4; ++k) {
    int j = tid + k * 1024;  // 0..4095 float4s of the 128x128 core
    int y = j >> 5;          // 32 float4 per core row
    int xq = j & 31;
    uint32_t v = sb32[(HALO + y) * (TILEX / 4) + (HALO / 4) + xq];
    float4 o;
    o.x = (float)(v & 0xFFu) - 1.0f;
    o.y = (float)((v >> 8) & 0xFFu) - 1.0f;
    o.z = (float)((v >> 16) & 0xFFu) - 1.0f;
    o.w = (float)(v >> 24) - 1.0f;
    *(float4*)(out + (size_t)(by * COREY + y) * HW + bx * COREX + xq * 4) = o;
  }
}

extern "C" void kernel_launch(void* const* d_in, const int* in_sizes, int n_in,
                              void* d_out, int out_size, void* d_ws, size_t ws_size,
                              hipStream_t stream) {
  const float* img = (const float*)d_in[0];
  float* out = (float*)d_out;
  char* ws = (char*)d_ws;

  float2* part = (float2*)ws;            // 8 KB (1024 float2)
  float* graw = (float*)(ws + 16384);    // 16.8 MB

  k_stage1<<<1024, 256, 0, stream>>>(img, graw, part);
  k_sweep<<<NBLK, 1024, 0, stream>>>(graw, part, out);
}